// Round 5
// baseline (3382.105 us; speedup 1.0000x reference)
//
#include <hip/hip_runtime.h>
#include <math.h>
#include <stddef.h>
#include <stdint.h>

// ---------------------------------------------------------------------------
// ReNet: patches -> vert bidir LSTM -> horiz bidir LSTM -> dense+relu
// B=64, I=J=32, D=12, HID=256, FC=1024.
// Round 5: round 4 + compile fix (nontemporal_store needs ext_vector types,
// not HIP_vector_type).
// ---------------------------------------------------------------------------

namespace {

typedef __bf16 bf16x8 __attribute__((ext_vector_type(8)));
typedef float f32x4 __attribute__((ext_vector_type(4)));
typedef unsigned int u32x4 __attribute__((ext_vector_type(4)));
typedef __attribute__((address_space(1))) unsigned int as1_uint;
typedef __attribute__((address_space(3))) unsigned int as3_uint;

__device__ __forceinline__ float bf2f(ushort u) {
  return __builtin_bit_cast(float, (unsigned int)u << 16);
}
__device__ __forceinline__ ushort f2bf(float f) {
  unsigned int u = __builtin_bit_cast(unsigned int, f);
  u += 0x7fffu + ((u >> 16) & 1u);
  return (ushort)(u >> 16);
}
__device__ __forceinline__ float sigm(float x) {
  return __fdividef(1.f, 1.f + __expf(-x));
}
__device__ __forceinline__ float tanh_(float x) {
  return 2.f * sigm(2.f * x) - 1.f;
}
__device__ __forceinline__ f32x4 mfma16(bf16x8 a, bf16x8 b, f32x4 c) {
  return __builtin_amdgcn_mfma_f32_16x16x32_bf16(a, b, c, 0, 0, 0);
}
__device__ __forceinline__ void load_lds16(const void* g, void* l) {
  __builtin_amdgcn_global_load_lds((const as1_uint*)g, (as3_uint*)l, 16, 0, 0);
}

// --------------------------------------------------------------------------
// transpose f32 [K][1024] -> bf16 [1024][K]
__global__ __launch_bounds__(256) void transpose_bf16(
    const float* __restrict__ in, ushort* __restrict__ out, int K) {
  const int idx = blockIdx.x * 256 + threadIdx.x;
  if (idx >= (K << 10)) return;
  const int n = idx / K, k = idx - n * K;
  out[idx] = f2bf(in[k * 1024 + n]);
}

// --------------------------------------------------------------------------
// Zv[dir][n=b*32+j][i][1024] = bias + p[(b,i,j)][0:12] @ k[12][1024]
__global__ __launch_bounds__(256) void zxv_kernel(
    const float* __restrict__ x, const float* __restrict__ k0_,
    const float* __restrict__ b0_, const float* __restrict__ k1_,
    const float* __restrict__ b1_, ushort* __restrict__ Z) {
  const int tid = threadIdx.x;
  const int j = blockIdx.x, b = blockIdx.y, dir = blockIdx.z;
  const float* kw_ = dir ? k1_ : k0_;
  const float* bw_ = dir ? b1_ : b0_;
  __shared__ float kw[12][1024];
  __shared__ float ps[32][12];
  for (int e = tid; e < 12 * 1024; e += 256) kw[e >> 10][e & 1023] = kw_[e];
  for (int e = tid; e < 32 * 12; e += 256) {
    const int i = e / 12, q = e - i * 12;
    const int pr = q / 6, rem = q - pr * 6;
    ps[i][q] = x[((size_t)((b * 64 + i * 2 + pr) * 64) + j * 2 + rem / 3) * 3 + rem % 3];
  }
  __syncthreads();
  const int col = tid << 2;
  float4 kr[12];
#pragma unroll
  for (int q = 0; q < 12; ++q) kr[q] = *(const float4*)&kw[q][col];
  const float4 bias4 = *(const float4*)&bw_[col];
  ushort* zb = Z + (((size_t)(dir * 2048 + b * 32 + j)) << 15) + col;
  for (int i = 0; i < 32; ++i) {
    float4 a = bias4;
#pragma unroll
    for (int q = 0; q < 12; ++q) {
      const float p = ps[i][q];
      a.x += p * kr[q].x; a.y += p * kr[q].y;
      a.z += p * kr[q].z; a.w += p * kr[q].w;
    }
    ushort4 o;
    o.x = f2bf(a.x); o.y = f2bf(a.y); o.z = f2bf(a.z); o.w = f2bf(a.w);
    *(ushort4*)(zb + ((size_t)i << 10)) = o;
  }
}

// --------------------------------------------------------------------------
// Persistent bidirectional LSTM sweep. Grid (32 rowblk, 8 hblk, 2 dir) = 512
// blocks = exactly 2/CU (64 KB LDS, launch_bounds(256,2)) -> all co-resident.
// Group = (rb, dir): the 8 hb blocks sharing rows [rb*64,+64). Per-step sync
// is an 8-arrival atomic counter per group (agent scope, release/acquire).
// Z: [2][2048][32][1024] bf16 (bias included).
// hbuf: [2 ping][2 dir][2048][256] bf16 (t=0 uses register zeros, no init).
// outbuf: [64][32][32][512] bf16. cnt: [64 groups][32 steps] uint, pre-zeroed.
__global__ __launch_bounds__(256, 2) void lstm_sweep_p(
    const ushort* __restrict__ Z, const ushort* __restrict__ rT,
    ushort* __restrict__ hbuf, ushort* __restrict__ outbuf,
    unsigned int* __restrict__ cnt, int vert) {
  const int tid = threadIdx.x;
  const int lane = tid & 63;
  const int l16 = lane & 15, kg = lane >> 4;
  const int wid = tid >> 6;
  const int wr = wid >> 1, wc = wid & 1;
  const int rb = blockIdx.x, hb = blockIdx.y, dir = (int)blockIdx.z;
  const int rowbase = rb << 6;
  unsigned int* gcnt = cnt + (((dir << 5) + rb) << 5);

  __shared__ uint4 rs[128][32];  // [local gate-col][k-chunk], XOR-swizzled

  // stage R tile (128 gate-cols x 256 k) ONCE per sweep
  for (int e = tid; e < 4096; e += 256) {
    const int cc = e >> 5, ch = e & 31;
    const int g = cc >> 5, u = cc & 31;
    const uint4* src =
        (const uint4*)(rT + ((size_t)dir * 1024 + (g << 8) + (hb << 5) + u) * 256);
    rs[cc][ch ^ (cc & 7)] = src[ch];
  }
  __syncthreads();

  const int hcol = (hb << 5) + (wc << 4) + l16;

  float cstate[2][4];
#pragma unroll
  for (int mt = 0; mt < 2; ++mt)
#pragma unroll
    for (int r = 0; r < 4; ++r) cstate[mt][r] = 0.f;

  for (int t = 0; t < 32; ++t) {
    const int seq = dir ? (31 - t) : t;

    // zx prefetch (independent of the barrier) -- issue before the spin
    float zx[2][4][4];
#pragma unroll
    for (int mt = 0; mt < 2; ++mt) {
#pragma unroll
      for (int r = 0; r < 4; ++r) {
        const int n = rowbase + (wr << 5) + (mt << 4) + (kg << 2) + r;
        const ushort* zp = Z + (((size_t)(dir * 2048 + n) * 32 + seq) << 10) + hcol;
#pragma unroll
        for (int g = 0; g < 4; ++g) zx[mt][g][r] = bf2f(zp[g << 8]);
      }
    }

    // wait until all 8 group members published h(t-1)
    if (t) {
      if (tid == 0) {
        while (__hip_atomic_load(gcnt + (t - 1), __ATOMIC_RELAXED,
                                 __HIP_MEMORY_SCOPE_AGENT) < 8u)
          __builtin_amdgcn_s_sleep(1);
        __threadfence();  // acquire
      }
      __syncthreads();
    }

    f32x4 acc[2][4];
#pragma unroll
    for (int mt = 0; mt < 2; ++mt)
#pragma unroll
      for (int g = 0; g < 4; ++g) acc[mt][g] = (f32x4){0.f, 0.f, 0.f, 0.f};

    if (t) {
      const ushort* hprev = hbuf + (size_t)(((t - 1) & 1) * 2 + dir) * 524288;
      uint4 af[2][8];
#pragma unroll
      for (int mt = 0; mt < 2; ++mt) {
        const int n = rowbase + (wr << 5) + (mt << 4) + l16;
#pragma unroll
        for (int kk = 0; kk < 8; ++kk)
          af[mt][kk] = *(const uint4*)(hprev + ((size_t)n << 8) + (kk << 5) + (kg << 3));
      }
#pragma unroll
      for (int kk = 0; kk < 8; ++kk) {
        const bf16x8 a0 = __builtin_bit_cast(bf16x8, af[0][kk]);
        const bf16x8 a1 = __builtin_bit_cast(bf16x8, af[1][kk]);
        const int q = (kk << 2) + kg;
#pragma unroll
        for (int g = 0; g < 4; ++g) {
          const int cc = (g << 5) + (wc << 4) + l16;
          const bf16x8 b = __builtin_bit_cast(bf16x8, rs[cc][q ^ (cc & 7)]);
          acc[0][g] = mfma16(a0, b, acc[0][g]);
          acc[1][g] = mfma16(a1, b, acc[1][g]);
        }
      }
    }

    // fused gate epilogue; h(t) -> ping (t&1)
    ushort* hnext = hbuf + (size_t)((t & 1) * 2 + dir) * 524288;
#pragma unroll
    for (int mt = 0; mt < 2; ++mt) {
#pragma unroll
      for (int r = 0; r < 4; ++r) {
        const int n = rowbase + (wr << 5) + (mt << 4) + (kg << 2) + r;
        const float zi = acc[mt][0][r] + zx[mt][0][r];
        const float zf = acc[mt][1][r] + zx[mt][1][r];
        const float zg = acc[mt][2][r] + zx[mt][2][r];
        const float zo = acc[mt][3][r] + zx[mt][3][r];
        const float cn = sigm(zf) * cstate[mt][r] + sigm(zi) * tanh_(zg);
        cstate[mt][r] = cn;
        const float hv = sigm(zo) * tanh_(cn);
        const ushort h16 = f2bf(hv);
        hnext[((size_t)n << 8) + hcol] = h16;
        const int b = n >> 5, sp = n & 31;
        const int X = vert ? seq : sp;
        const int Y = vert ? sp : seq;
        outbuf[(((size_t)(b * 32 + X) * 32 + Y) << 9) + (dir << 8) + hcol] = h16;
      }
    }

    // publish h(t)
    if (t < 31) {
      __syncthreads();
      if (tid == 0) {
        __threadfence();
        __hip_atomic_fetch_add(gcnt + t, 1u, __ATOMIC_RELAXED,
                               __HIP_MEMORY_SCOPE_AGENT);
      }
    }
  }
}

// --------------------------------------------------------------------------
// C[M=65536][1024] = A[M][512] @ BT[1024][512]^T + bias ; EPI 0: bf16 store,
// EPI 1: relu f32 store. 128x128 tile, BK=64, global_load_lds + XOR swizzle.
// Block remap: XCD (bid&7) owns m-tiles [xcd*64,+64), n fastest -> A read
// ~once from HBM. Epilogue staged through LDS for coalesced 16B nt-stores.
template <int EPI>
__global__ __launch_bounds__(256) void gemm_bt(
    const ushort* __restrict__ A, const ushort* __restrict__ BT,
    const float* __restrict__ bias, void* __restrict__ Cv) {
  const int tid = threadIdx.x;
  const int lane = tid & 63, wid = tid >> 6;
  const int l16 = lane & 15, kg = lane >> 4;
  const int wr = wid >> 1, wc = wid & 1;
  const int bid = blockIdx.x;
  const int xcd = bid & 7, lid = bid >> 3;
  const int m0 = ((xcd << 6) + (lid >> 3)) << 7;
  const int n0 = (lid & 7) << 7;

  union SM {
    struct { uint4 A[128][8]; uint4 B[128][8]; } k;
    ushort eh[64][136];
    float ef[64][132];
  };
  __shared__ SM sm;

  f32x4 acc[4][4];
#pragma unroll
  for (int mt = 0; mt < 4; ++mt)
#pragma unroll
    for (int nt = 0; nt < 4; ++nt) acc[mt][nt] = (f32x4){0.f, 0.f, 0.f, 0.f};

  for (int k0 = 0; k0 < 512; k0 += 64) {
#pragma unroll
    for (int c = 0; c < 4; ++c) {
      const int cid = (wid << 8) + (c << 6) + lane;
      const int row = cid >> 3, ch = cid & 7;
      const int sch = ch ^ (row & 7);  // pre-swizzled source (rule 21)
      load_lds16(A + (size_t)(m0 + row) * 512 + k0 + (sch << 3),
                 (uint4*)sm.k.A + (cid - lane));
      load_lds16(BT + (size_t)(n0 + row) * 512 + k0 + (sch << 3),
                 (uint4*)sm.k.B + (cid - lane));
    }
    __syncthreads();
#pragma unroll
    for (int kk = 0; kk < 2; ++kk) {
      const int q = (kk << 2) + kg;
      bf16x8 a[4], b[4];
#pragma unroll
      for (int mt = 0; mt < 4; ++mt) {
        const int rr = (wr << 6) + (mt << 4) + l16;
        a[mt] = __builtin_bit_cast(bf16x8, sm.k.A[rr][q ^ (rr & 7)]);
      }
#pragma unroll
      for (int nt = 0; nt < 4; ++nt) {
        const int rr = (wc << 6) + (nt << 4) + l16;
        b[nt] = __builtin_bit_cast(bf16x8, sm.k.B[rr][q ^ (rr & 7)]);
      }
#pragma unroll
      for (int mt = 0; mt < 4; ++mt)
#pragma unroll
        for (int nt = 0; nt < 4; ++nt)
          acc[mt][nt] = mfma16(a[mt], b[nt], acc[mt][nt]);
    }
    __syncthreads();
  }

  float bn[4];
#pragma unroll
  for (int nt = 0; nt < 4; ++nt)
    bn[nt] = bias[n0 + (wc << 6) + (nt << 4) + l16];

#pragma unroll
  for (int h = 0; h < 2; ++h) {
    __syncthreads();
    if (wr == h) {  // waves wr==h own rows [h*64, h*64+64) of the tile
#pragma unroll
      for (int nt = 0; nt < 4; ++nt) {
        const int col = (wc << 6) + (nt << 4) + l16;
#pragma unroll
        for (int mt = 0; mt < 4; ++mt) {
#pragma unroll
          for (int r = 0; r < 4; ++r) {
            const int rowl = (mt << 4) + (kg << 2) + r;
            const float v = acc[mt][nt][r] + bn[nt];
            if (EPI == 0)
              sm.eh[rowl][col] = f2bf(v);
            else
              sm.ef[rowl][col] = fmaxf(v, 0.f);
          }
        }
      }
    }
    __syncthreads();
    if (EPI == 0) {
      ushort* out = (ushort*)Cv;
#pragma unroll
      for (int q = 0; q < 4; ++q) {
        const int c = tid + (q << 8);
        const int row = c >> 4, co = (c & 15) << 3;
        const u32x4 v = *(const u32x4*)&sm.eh[row][co];
        __builtin_nontemporal_store(
            v, (u32x4*)(out + (size_t)(m0 + (h << 6) + row) * 1024 + n0 + co));
      }
    } else {
      float* out = (float*)Cv;
#pragma unroll
      for (int q = 0; q < 8; ++q) {
        const int c = tid + (q << 8);
        const int row = c >> 5, co = (c & 31) << 2;
        const f32x4 v = *(const f32x4*)&sm.ef[row][co];
        __builtin_nontemporal_store(
            v, (f32x4*)(out + (size_t)(m0 + (h << 6) + row) * 1024 + n0 + co));
      }
    }
  }
}

}  // namespace

extern "C" void kernel_launch(void* const* d_in, const int* in_sizes, int n_in,
                              void* d_out, int out_size, void* d_ws, size_t ws_size,
                              hipStream_t stream) {
  (void)in_sizes; (void)n_in; (void)out_size; (void)ws_size;
  const float* x    = (const float*)d_in[0];
  const float* k_ud = (const float*)d_in[1];
  const float* r_ud = (const float*)d_in[2];
  const float* b_ud = (const float*)d_in[3];
  const float* k_du = (const float*)d_in[4];
  const float* r_du = (const float*)d_in[5];
  const float* b_du = (const float*)d_in[6];
  const float* k_lr = (const float*)d_in[7];
  const float* r_lr = (const float*)d_in[8];
  const float* b_lr = (const float*)d_in[9];
  const float* k_rl = (const float*)d_in[10];
  const float* r_rl = (const float*)d_in[11];
  const float* b_rl = (const float*)d_in[12];
  const float* Wd   = (const float*)d_in[13];
  const float* bd   = (const float*)d_in[14];

  ushort* W     = (ushort*)d_ws;
  ushort* Z     = W;                      // [2][2048][32][1024]  134217728
  ushort* vbuf  = Z + 134217728;          // [64][32][32][512]     33554432 (also hfin)
  ushort* hping = vbuf + 33554432;        // [2 ping][2 dir][2048][256]  2097152
  ushort* rT    = hping + 2097152;        // [4][1024][256]         1048576
  ushort* kTh   = rT + 1048576;           // [2][1024][512]         1048576
  ushort* WdT   = kTh + 1048576;          // [1024][512]             524288
  unsigned int* cnt = (unsigned int*)(WdT + 524288);  // [2 sweeps][64][32]

  // barrier counters must be zero at each sweep start (re-zeroed every replay)
  (void)hipMemsetAsync(cnt, 0, 4096 * sizeof(unsigned int), stream);

  // ---- weight prep (transpose to [N][K] bf16) ----
  transpose_bf16<<<1024, 256, 0, stream>>>(r_ud, rT, 256);
  transpose_bf16<<<1024, 256, 0, stream>>>(r_du, rT + 262144, 256);
  transpose_bf16<<<1024, 256, 0, stream>>>(r_lr, rT + 524288, 256);
  transpose_bf16<<<1024, 256, 0, stream>>>(r_rl, rT + 786432, 256);
  transpose_bf16<<<2048, 256, 0, stream>>>(k_lr, kTh, 512);
  transpose_bf16<<<2048, 256, 0, stream>>>(k_rl, kTh + 524288, 512);
  transpose_bf16<<<2048, 256, 0, stream>>>(Wd, WdT, 512);

  // ---- vertical input projection (K=12) ----
  zxv_kernel<<<dim3(32, 64, 2), 256, 0, stream>>>(x, k_ud, b_ud, k_du, b_du, Z);

  // ---- vertical sweep (persistent) ----
  lstm_sweep_p<<<dim3(32, 8, 2), 256, 0, stream>>>(Z, rT, hping, vbuf, cnt, 1);

  // ---- horizontal input projection: Z = v @ k + b (per dir) ----
  gemm_bt<0><<<4096, 256, 0, stream>>>(vbuf, kTh, b_lr, (void*)Z);
  gemm_bt<0><<<4096, 256, 0, stream>>>(vbuf, kTh + 524288, b_rl,
                                       (void*)(Z + 67108864));

  // ---- horizontal sweep (persistent; writes hfin over vbuf, reads only Z) --
  lstm_sweep_p<<<dim3(32, 8, 2), 256, 0, stream>>>(Z, rT + 524288, hping, vbuf,
                                                   cnt + 2048, 0);

  // ---- dense + relu ----
  gemm_bt<1><<<4096, 256, 0, stream>>>(vbuf, WdT, bd, d_out);
}

// Round 6
// 2581.082 us; speedup vs baseline: 1.3103x; 1.3103x over previous
//
#include <hip/hip_runtime.h>
#include <math.h>
#include <stddef.h>
#include <stdint.h>

// ---------------------------------------------------------------------------
// ReNet: patches -> vert bidir LSTM -> horiz bidir LSTM -> dense+relu
// B=64, I=J=32, D=12, HID=256, FC=1024.
// Round 6: self-contained LSTM blocks (64 rows x all 256 h) -> h stays in
// LDS, no inter-block sync. R in fragment-major layout streamed from L2.
// zx folded into MFMA accumulator init via row-pair-interleaved Z layout.
// ---------------------------------------------------------------------------

namespace {

typedef __bf16 bf16x8 __attribute__((ext_vector_type(8)));
typedef float f32x4 __attribute__((ext_vector_type(4)));
typedef unsigned int u32x4 __attribute__((ext_vector_type(4)));
typedef __attribute__((address_space(1))) unsigned int as1_uint;
typedef __attribute__((address_space(3))) unsigned int as3_uint;

__device__ __forceinline__ float bf2f(ushort u) {
  return __builtin_bit_cast(float, (unsigned int)u << 16);
}
__device__ __forceinline__ ushort f2bf(float f) {
  unsigned int u = __builtin_bit_cast(unsigned int, f);
  u += 0x7fffu + ((u >> 16) & 1u);
  return (ushort)(u >> 16);
}
__device__ __forceinline__ float sigm(float x) {
  return __fdividef(1.f, 1.f + __expf(-x));
}
__device__ __forceinline__ float tanh_(float x) {
  return 2.f * sigm(2.f * x) - 1.f;
}
__device__ __forceinline__ f32x4 mfma16(bf16x8 a, bf16x8 b, f32x4 c) {
  return __builtin_amdgcn_mfma_f32_16x16x32_bf16(a, b, c, 0, 0, 0);
}
__device__ __forceinline__ void load_lds16(const void* g, void* l) {
  __builtin_amdgcn_global_load_lds((const as1_uint*)g, (as3_uint*)l, 16, 0, 0);
}

// --------------------------------------------------------------------------
// transpose f32 [K][1024] -> bf16 [1024][K]  (for gemm B operands)
__global__ __launch_bounds__(256) void transpose_bf16(
    const float* __restrict__ in, ushort* __restrict__ out, int K) {
  const int idx = blockIdx.x * 256 + threadIdx.x;
  if (idx >= (K << 10)) return;
  const int n = idx / K, k = idx - n * K;
  out[idx] = f2bf(in[k * 1024 + n]);
}

// --------------------------------------------------------------------------
// Repack recurrent weights r [256][1024] f32 into MFMA B-fragment-major bf16:
// out[tile=gc/16 (64)][kc (8)][lane (64)][8], elem j = r[kc*32+(lane>>4)*8+j]
//                                                      [tile*16 + (lane&15)]
__global__ __launch_bounds__(256) void rfrag_kernel(
    const float* __restrict__ r, ushort* __restrict__ out) {
  const int id = blockIdx.x * 256 + threadIdx.x;  // 32768 ids
  const int lane = id & 63, kc = (id >> 6) & 7, tile = id >> 9;
  const int kbase = (kc << 5) + ((lane >> 4) << 3);
  const int col = (tile << 4) + (lane & 15);
  ushort tmp[8];
#pragma unroll
  for (int j = 0; j < 8; ++j) tmp[j] = f2bf(r[(size_t)(kbase + j) * 1024 + col]);
  *(uint4*)&out[(size_t)id << 3] = *(const uint4*)tmp;
}

// --------------------------------------------------------------------------
// Vertical input projection into pair-interleaved Z:
// Zu (uint view) [dir][n2=1024][seq=32][col=1024], uint = (bf16 row even,
// bf16 row odd). Rows n = b*32+j, seq = i. Block = (jpair, b, dir).
__global__ __launch_bounds__(256) void zxv2_kernel(
    const float* __restrict__ x, const float* __restrict__ k0_,
    const float* __restrict__ b0_, const float* __restrict__ k1_,
    const float* __restrict__ b1_, unsigned int* __restrict__ Zu) {
  const int tid = threadIdx.x;
  const int jp = blockIdx.x, b = blockIdx.y, dir = blockIdx.z;
  const int j0 = jp << 1;
  const float* kw_ = dir ? k1_ : k0_;
  const float* bw_ = dir ? b1_ : b0_;
  __shared__ float kw[12][1024];
  __shared__ float ps[2][32][12];
  for (int e = tid; e < 12 * 1024; e += 256) kw[e >> 10][e & 1023] = kw_[e];
  for (int e = tid; e < 2 * 32 * 12; e += 256) {
    const int jj = e / 384, rest = e - jj * 384;
    const int i = rest / 12, q = rest - i * 12;
    const int pr = q / 6, rem = q - pr * 6;
    ps[jj][i][q] = x[((size_t)((b * 64 + i * 2 + pr) * 64) + (j0 + jj) * 2 + rem / 3) * 3 + rem % 3];
  }
  __syncthreads();
  const int col = tid << 2;
  float4 kr[12];
#pragma unroll
  for (int q = 0; q < 12; ++q) kr[q] = *(const float4*)&kw[q][col];
  const float4 bias4 = *(const float4*)&bw_[col];
  const int n2 = b * 16 + jp;
  unsigned int* zb = Zu + ((size_t)(dir * 1024 + n2) << 15) + col;
  for (int i = 0; i < 32; ++i) {
    float4 a0 = bias4, a1 = bias4;
#pragma unroll
    for (int q = 0; q < 12; ++q) {
      const float p0 = ps[0][i][q], p1 = ps[1][i][q];
      a0.x += p0 * kr[q].x; a0.y += p0 * kr[q].y;
      a0.z += p0 * kr[q].z; a0.w += p0 * kr[q].w;
      a1.x += p1 * kr[q].x; a1.y += p1 * kr[q].y;
      a1.z += p1 * kr[q].z; a1.w += p1 * kr[q].w;
    }
    uint4 o;
    o.x = (unsigned int)f2bf(a0.x) | ((unsigned int)f2bf(a1.x) << 16);
    o.y = (unsigned int)f2bf(a0.y) | ((unsigned int)f2bf(a1.y) << 16);
    o.z = (unsigned int)f2bf(a0.z) | ((unsigned int)f2bf(a1.z) << 16);
    o.w = (unsigned int)f2bf(a0.w) | ((unsigned int)f2bf(a1.w) << 16);
    *(uint4*)(zb + ((size_t)i << 10)) = o;
  }
}

// --------------------------------------------------------------------------
// Self-contained bidirectional LSTM sweep. Grid (32 rowblk, 2 dir) = 64
// blocks, 512 threads (8 waves). Block owns rows [rb*64,+64) x ALL 256 h.
// Wave w owns h-cols [w*32,+32) x 4 gates. h kept in LDS (XOR-swizzled);
// R streamed fragment-major from L2; zx = accumulator init (pair layout).
// outbuf: [64][32][32][512] bf16 (vert: [b][seq][sp], horiz: [b][sp][seq]).
__global__ __launch_bounds__(512, 2) void lstm_sweep2(
    const unsigned int* __restrict__ Zu, const uint4* __restrict__ rF,
    ushort* __restrict__ outbuf, int vert) {
  const int tid = threadIdx.x;
  const int lane = tid & 63, w = tid >> 6;
  const int l16 = lane & 15, kg = lane >> 4;
  const int rb = blockIdx.x, dir = (int)blockIdx.y;
  const int rowbase = rb << 6;

  __shared__ ushort hlds[64 * 256];  // 32 KB, 16B chunks XOR-swizzled by row&7

  const uint4* rFd = rF + (size_t)dir * 32768;  // [64][8][64] uint4
  const unsigned int* zbase =
      Zu + (((size_t)dir * 1024 + (rowbase >> 1)) << 15);

  float cst[4][2][4];
#pragma unroll
  for (int mt = 0; mt < 4; ++mt)
#pragma unroll
    for (int q = 0; q < 2; ++q)
#pragma unroll
      for (int r = 0; r < 4; ++r) cst[mt][q][r] = 0.f;

  for (int t = 0; t < 32; ++t) {
    const int seq = dir ? (31 - t) : t;

    // ---- acc init = zx (pair-interleaved loads) ----
    f32x4 acc[4][8];
#pragma unroll
    for (int mt = 0; mt < 4; ++mt) {
#pragma unroll
      for (int nt = 0; nt < 8; ++nt) {
        const int g = nt >> 1, q = nt & 1;
        const int col = (g << 8) + (w << 5) + (q << 4) + l16;
#pragma unroll
        for (int p = 0; p < 2; ++p) {
          const int n2l = (mt << 3) + (kg << 1) + p;
          const unsigned int z2 = zbase[(((size_t)n2l << 5) + seq << 10) + col];
          acc[mt][nt][2 * p] = bf2f((ushort)(z2 & 0xffffu));
          acc[mt][nt][2 * p + 1] = bf2f((ushort)(z2 >> 16));
        }
      }
    }

    // ---- MFMA: acc += h(t-1) @ R ----
    if (t) {
#pragma unroll
      for (int kc = 0; kc < 8; ++kc) {
        uint4 a[4];
#pragma unroll
        for (int mt = 0; mt < 4; ++mt) {
          const int row = (mt << 4) + l16;
          const int c4 = (kc << 2) + kg;
          a[mt] = *(const uint4*)((const char*)hlds + row * 512 +
                                  ((c4 ^ (row & 7)) << 4));
        }
        uint4 bfr[8];
#pragma unroll
        for (int nt = 0; nt < 8; ++nt) {
          const int tile = ((nt >> 1) << 4) + (w << 1) + (nt & 1);
          bfr[nt] = rFd[((size_t)tile << 3 | kc) * 64 + lane];
        }
#pragma unroll
        for (int mt = 0; mt < 4; ++mt)
#pragma unroll
          for (int nt = 0; nt < 8; ++nt)
            acc[mt][nt] = mfma16(__builtin_bit_cast(bf16x8, a[mt]),
                                 __builtin_bit_cast(bf16x8, bfr[nt]),
                                 acc[mt][nt]);
      }
    }
    __syncthreads();  // all h(t-1) reads done

    // ---- fused gate epilogue -> h(t) into LDS ----
#pragma unroll
    for (int mt = 0; mt < 4; ++mt) {
#pragma unroll
      for (int q = 0; q < 2; ++q) {
        const int col = (w << 5) + (q << 4) + l16;
#pragma unroll
        for (int r = 0; r < 4; ++r) {
          const float zi = acc[mt][q][r];
          const float zf = acc[mt][2 + q][r];
          const float zg = acc[mt][4 + q][r];
          const float zo = acc[mt][6 + q][r];
          const float cn = sigm(zf) * cst[mt][q][r] + sigm(zi) * tanh_(zg);
          cst[mt][q][r] = cn;
          const float hv = sigm(zo) * tanh_(cn);
          const int row = (mt << 4) + (kg << 2) + r;
          *(ushort*)((char*)hlds + row * 512 +
                     (((col >> 3) ^ (row & 7)) << 4) + ((col & 7) << 1)) =
              f2bf(hv);
        }
      }
    }
    __syncthreads();  // h(t) complete

    // ---- coalesced LDS -> outbuf copy (overlaps next step) ----
#pragma unroll
    for (int it = 0; it < 4; ++it) {
      const int c = (tid << 2) + it;  // chunk 0..2047
      const int row = c >> 5, c4 = c & 31;
      const uint4 v =
          *(const uint4*)((const char*)hlds + row * 512 + ((c4 ^ (row & 7)) << 4));
      const int n = rowbase + row, b = n >> 5, sp = n & 31;
      const int X = vert ? seq : sp;
      const int Y = vert ? sp : seq;
      *(uint4*)&outbuf[(((size_t)(b * 32 + X) * 32 + Y) << 9) + (dir << 8) +
                       (c4 << 3)] = v;
    }
  }
}

// --------------------------------------------------------------------------
// C = A[M][512] @ BT[1024][512]^T + bias. 128x128 tile, BK=64,
// global_load_lds + XOR swizzle, XCD-aware remap, LDS-staged epilogue.
// EPI 0: pair-interleaved Z store (uint = bf16 row-even | row-odd<<16).
// EPI 1: relu f32 store.
template <int EPI>
__global__ __launch_bounds__(256) void gemm_bt(
    const ushort* __restrict__ A, const ushort* __restrict__ BT,
    const float* __restrict__ bias, void* __restrict__ Cv) {
  const int tid = threadIdx.x;
  const int lane = tid & 63, wid = tid >> 6;
  const int l16 = lane & 15, kg = lane >> 4;
  const int wr = wid >> 1, wc = wid & 1;
  const int bid = blockIdx.x;
  const int xcd = bid & 7, lid = bid >> 3;
  const int m0 = ((xcd << 6) + (lid >> 3)) << 7;
  const int n0 = (lid & 7) << 7;

  union SM {
    struct { uint4 A[128][8]; uint4 B[128][8]; } k;
    ushort eh[64][136];
    float ef[64][132];
  };
  __shared__ SM sm;

  f32x4 acc[4][4];
#pragma unroll
  for (int mt = 0; mt < 4; ++mt)
#pragma unroll
    for (int nt = 0; nt < 4; ++nt) acc[mt][nt] = (f32x4){0.f, 0.f, 0.f, 0.f};

  for (int k0 = 0; k0 < 512; k0 += 64) {
#pragma unroll
    for (int c = 0; c < 4; ++c) {
      const int cid = (wid << 8) + (c << 6) + lane;
      const int row = cid >> 3, ch = cid & 7;
      const int sch = ch ^ (row & 7);
      load_lds16(A + (size_t)(m0 + row) * 512 + k0 + (sch << 3),
                 (uint4*)sm.k.A + (cid - lane));
      load_lds16(BT + (size_t)(n0 + row) * 512 + k0 + (sch << 3),
                 (uint4*)sm.k.B + (cid - lane));
    }
    __syncthreads();
#pragma unroll
    for (int kk = 0; kk < 2; ++kk) {
      const int q = (kk << 2) + kg;
      bf16x8 a[4], b[4];
#pragma unroll
      for (int mt = 0; mt < 4; ++mt) {
        const int rr = (wr << 6) + (mt << 4) + l16;
        a[mt] = __builtin_bit_cast(bf16x8, sm.k.A[rr][q ^ (rr & 7)]);
      }
#pragma unroll
      for (int nt = 0; nt < 4; ++nt) {
        const int rr = (wc << 6) + (nt << 4) + l16;
        b[nt] = __builtin_bit_cast(bf16x8, sm.k.B[rr][q ^ (rr & 7)]);
      }
#pragma unroll
      for (int mt = 0; mt < 4; ++mt)
#pragma unroll
        for (int nt = 0; nt < 4; ++nt)
          acc[mt][nt] = mfma16(a[mt], b[nt], acc[mt][nt]);
    }
    __syncthreads();
  }

  float bn[4];
#pragma unroll
  for (int nt = 0; nt < 4; ++nt)
    bn[nt] = bias[n0 + (wc << 6) + (nt << 4) + l16];

#pragma unroll
  for (int h = 0; h < 2; ++h) {
    __syncthreads();
    if (wr == h) {
#pragma unroll
      for (int nt = 0; nt < 4; ++nt) {
        const int col = (wc << 6) + (nt << 4) + l16;
#pragma unroll
        for (int mt = 0; mt < 4; ++mt) {
#pragma unroll
          for (int r = 0; r < 4; ++r) {
            const int rowl = (mt << 4) + (kg << 2) + r;
            const float v = acc[mt][nt][r] + bn[nt];
            if (EPI == 0)
              sm.eh[rowl][col] = f2bf(v);
            else
              sm.ef[rowl][col] = fmaxf(v, 0.f);
          }
        }
      }
    }
    __syncthreads();
    if (EPI == 0) {
      // rows of this half = i-pair {2h, 2h+1} x 32 seq (m = n*32 + seq)
      unsigned int* out = (unsigned int*)Cv;
      const int n2 = (m0 >> 6) + h;
#pragma unroll
      for (int it = 0; it < 16; ++it) {
        const int e = tid + (it << 8);  // 0..4095
        const int seq = e >> 7, col = e & 127;
        const unsigned int v0 = sm.eh[seq][col];
        const unsigned int v1 = sm.eh[32 + seq][col];
        out[((size_t)(n2 * 32 + seq) << 10) + n0 + col] = v0 | (v1 << 16);
      }
    } else {
      float* out = (float*)Cv;
#pragma unroll
      for (int q = 0; q < 8; ++q) {
        const int c = tid + (q << 8);
        const int row = c >> 5, co = (c & 31) << 2;
        const f32x4 v = *(const f32x4*)&sm.ef[row][co];
        __builtin_nontemporal_store(
            v, (f32x4*)(out + (size_t)(m0 + (h << 6) + row) * 1024 + n0 + co));
      }
    }
  }
}

}  // namespace

extern "C" void kernel_launch(void* const* d_in, const int* in_sizes, int n_in,
                              void* d_out, int out_size, void* d_ws, size_t ws_size,
                              hipStream_t stream) {
  (void)in_sizes; (void)n_in; (void)out_size; (void)ws_size;
  const float* x    = (const float*)d_in[0];
  const float* k_ud = (const float*)d_in[1];
  const float* r_ud = (const float*)d_in[2];
  const float* b_ud = (const float*)d_in[3];
  const float* k_du = (const float*)d_in[4];
  const float* r_du = (const float*)d_in[5];
  const float* b_du = (const float*)d_in[6];
  const float* k_lr = (const float*)d_in[7];
  const float* r_lr = (const float*)d_in[8];
  const float* b_lr = (const float*)d_in[9];
  const float* k_rl = (const float*)d_in[10];
  const float* r_rl = (const float*)d_in[11];
  const float* b_rl = (const float*)d_in[12];
  const float* Wd   = (const float*)d_in[13];
  const float* bd   = (const float*)d_in[14];

  ushort* W    = (ushort*)d_ws;
  ushort* Z    = W;                      // [2][1024 n2][32][1024][2]  134217728
  ushort* vbuf = Z + 134217728;          // [64][32][32][512]           33554432
  ushort* rF   = vbuf + 33554432;        // [4][64][8][64][8]            1048576
  ushort* kTh  = rF + 1048576;           // [2][1024][512]               1048576
  ushort* WdT  = kTh + 1048576;          // [1024][512]                   524288

  // ---- weight prep ----
  rfrag_kernel<<<128, 256, 0, stream>>>(r_ud, rF);
  rfrag_kernel<<<128, 256, 0, stream>>>(r_du, rF + 262144);
  rfrag_kernel<<<128, 256, 0, stream>>>(r_lr, rF + 524288);
  rfrag_kernel<<<128, 256, 0, stream>>>(r_rl, rF + 786432);
  transpose_bf16<<<2048, 256, 0, stream>>>(k_lr, kTh, 512);
  transpose_bf16<<<2048, 256, 0, stream>>>(k_rl, kTh + 524288, 512);
  transpose_bf16<<<2048, 256, 0, stream>>>(Wd, WdT, 512);

  // ---- vertical input projection (K=12), pair-interleaved Z ----
  zxv2_kernel<<<dim3(16, 64, 2), 256, 0, stream>>>(x, k_ud, b_ud, k_du, b_du,
                                                   (unsigned int*)Z);

  // ---- vertical sweep ----
  lstm_sweep2<<<dim3(32, 2), 512, 0, stream>>>((const unsigned int*)Z,
                                               (const uint4*)rF, vbuf, 1);

  // ---- horizontal input projection: Z = v @ k + b (per dir) ----
  gemm_bt<0><<<4096, 256, 0, stream>>>(vbuf, kTh, b_lr, (void*)Z);
  gemm_bt<0><<<4096, 256, 0, stream>>>(vbuf, kTh + 524288, b_rl,
                                       (void*)(Z + 67108864));

  // ---- horizontal sweep (writes hfin over vbuf; reads only Z) ----
  lstm_sweep2<<<dim3(32, 2), 512, 0, stream>>>(
      (const unsigned int*)Z, (const uint4*)(rF + 524288), vbuf, 0);

  // ---- dense + relu ----
  gemm_bt<1><<<4096, 256, 0, stream>>>(vbuf, WdT, bd, d_out);
}

// Round 7
// 2554.734 us; speedup vs baseline: 1.3239x; 1.0103x over previous
//
#include <hip/hip_runtime.h>
#include <math.h>
#include <stddef.h>
#include <stdint.h>

// ---------------------------------------------------------------------------
// ReNet: patches -> vert bidir LSTM -> horiz bidir LSTM -> dense+relu
// B=64, I=J=32, D=12, HID=256, FC=1024.
// Round 7: sweep rebuilt for latency hiding: zx added post-MFMA (loads hidden
// under MFMA), split-q two-pass acc (low VGPR), R kc+1 prefetch, LDS h
// double-buffer with ONE barrier/step, direct reg->global out stores.
// ---------------------------------------------------------------------------

namespace {

typedef __bf16 bf16x8 __attribute__((ext_vector_type(8)));
typedef float f32x4 __attribute__((ext_vector_type(4)));
typedef unsigned int u32x4 __attribute__((ext_vector_type(4)));
typedef __attribute__((address_space(1))) unsigned int as1_uint;
typedef __attribute__((address_space(3))) unsigned int as3_uint;

__device__ __forceinline__ float bf2f(ushort u) {
  return __builtin_bit_cast(float, (unsigned int)u << 16);
}
__device__ __forceinline__ ushort f2bf(float f) {
  unsigned int u = __builtin_bit_cast(unsigned int, f);
  u += 0x7fffu + ((u >> 16) & 1u);
  return (ushort)(u >> 16);
}
__device__ __forceinline__ float sigm(float x) {
  return __fdividef(1.f, 1.f + __expf(-x));
}
__device__ __forceinline__ float tanh_(float x) {
  return 2.f * sigm(2.f * x) - 1.f;
}
__device__ __forceinline__ f32x4 mfma16(bf16x8 a, bf16x8 b, f32x4 c) {
  return __builtin_amdgcn_mfma_f32_16x16x32_bf16(a, b, c, 0, 0, 0);
}
__device__ __forceinline__ void load_lds16(const void* g, void* l) {
  __builtin_amdgcn_global_load_lds((const as1_uint*)g, (as3_uint*)l, 16, 0, 0);
}

// --------------------------------------------------------------------------
// transpose f32 [K][1024] -> bf16 [1024][K]  (for gemm B operands)
__global__ __launch_bounds__(256) void transpose_bf16(
    const float* __restrict__ in, ushort* __restrict__ out, int K) {
  const int idx = blockIdx.x * 256 + threadIdx.x;
  if (idx >= (K << 10)) return;
  const int n = idx / K, k = idx - n * K;
  out[idx] = f2bf(in[k * 1024 + n]);
}

// --------------------------------------------------------------------------
// Repack recurrent weights r [256][1024] f32 into MFMA B-fragment-major bf16:
// out[tile=gc/16 (64)][kc (8)][lane (64)][8], elem j = r[kc*32+(lane>>4)*8+j]
//                                                      [tile*16 + (lane&15)]
__global__ __launch_bounds__(256) void rfrag_kernel(
    const float* __restrict__ r, ushort* __restrict__ out) {
  const int id = blockIdx.x * 256 + threadIdx.x;  // 32768 ids
  const int lane = id & 63, kc = (id >> 6) & 7, tile = id >> 9;
  const int kbase = (kc << 5) + ((lane >> 4) << 3);
  const int col = (tile << 4) + (lane & 15);
  ushort tmp[8];
#pragma unroll
  for (int j = 0; j < 8; ++j) tmp[j] = f2bf(r[(size_t)(kbase + j) * 1024 + col]);
  *(uint4*)&out[(size_t)id << 3] = *(const uint4*)tmp;
}

// --------------------------------------------------------------------------
// Vertical input projection into pair-interleaved Z:
// Zu (uint view) [dir][n2=1024][seq=32][col=1024], uint = (bf16 row even,
// bf16 row odd). Rows n = b*32+j, seq = i. Block = (jpair, b, dir).
__global__ __launch_bounds__(256) void zxv2_kernel(
    const float* __restrict__ x, const float* __restrict__ k0_,
    const float* __restrict__ b0_, const float* __restrict__ k1_,
    const float* __restrict__ b1_, unsigned int* __restrict__ Zu) {
  const int tid = threadIdx.x;
  const int jp = blockIdx.x, b = blockIdx.y, dir = blockIdx.z;
  const int j0 = jp << 1;
  const float* kw_ = dir ? k1_ : k0_;
  const float* bw_ = dir ? b1_ : b0_;
  __shared__ float kw[12][1024];
  __shared__ float ps[2][32][12];
  for (int e = tid; e < 12 * 1024; e += 256) kw[e >> 10][e & 1023] = kw_[e];
  for (int e = tid; e < 2 * 32 * 12; e += 256) {
    const int jj = e / 384, rest = e - jj * 384;
    const int i = rest / 12, q = rest - i * 12;
    const int pr = q / 6, rem = q - pr * 6;
    ps[jj][i][q] = x[((size_t)((b * 64 + i * 2 + pr) * 64) + (j0 + jj) * 2 + rem / 3) * 3 + rem % 3];
  }
  __syncthreads();
  const int col = tid << 2;
  float4 kr[12];
#pragma unroll
  for (int q = 0; q < 12; ++q) kr[q] = *(const float4*)&kw[q][col];
  const float4 bias4 = *(const float4*)&bw_[col];
  const int n2 = b * 16 + jp;
  unsigned int* zb = Zu + ((size_t)(dir * 1024 + n2) << 15) + col;
  for (int i = 0; i < 32; ++i) {
    float4 a0 = bias4, a1 = bias4;
#pragma unroll
    for (int q = 0; q < 12; ++q) {
      const float p0 = ps[0][i][q], p1 = ps[1][i][q];
      a0.x += p0 * kr[q].x; a0.y += p0 * kr[q].y;
      a0.z += p0 * kr[q].z; a0.w += p0 * kr[q].w;
      a1.x += p1 * kr[q].x; a1.y += p1 * kr[q].y;
      a1.z += p1 * kr[q].z; a1.w += p1 * kr[q].w;
    }
    uint4 o;
    o.x = (unsigned int)f2bf(a0.x) | ((unsigned int)f2bf(a1.x) << 16);
    o.y = (unsigned int)f2bf(a0.y) | ((unsigned int)f2bf(a1.y) << 16);
    o.z = (unsigned int)f2bf(a0.z) | ((unsigned int)f2bf(a1.z) << 16);
    o.w = (unsigned int)f2bf(a0.w) | ((unsigned int)f2bf(a1.w) << 16);
    *(uint4*)(zb + ((size_t)i << 10)) = o;
  }
}

// --------------------------------------------------------------------------
// Self-contained bidirectional LSTM sweep, round 7.
// Grid (32 rowblk, 2 dir) = 64 blocks, 512 threads (8 waves, 2/SIMD).
// Block owns rows [rb*64,+64) x ALL 256 h. Wave w owns h-cols [w*32,+32).
// Two passes per step (q = col-16-halves): 32 zx loads issued early, awaited
// AFTER the MFMA chain; R fragments prefetched kc+1; h double-buffered in
// LDS with one barrier per step; out written straight from registers.
__global__ __launch_bounds__(512, 2) void lstm_sweep3(
    const unsigned int* __restrict__ Zu, const uint4* __restrict__ rF,
    ushort* __restrict__ outbuf, int vert) {
  const int tid = threadIdx.x;
  const int lane = tid & 63, w = tid >> 6;
  const int l16 = lane & 15, kg = lane >> 4;
  const int rb = blockIdx.x, dir = (int)blockIdx.y;
  const int rowbase = rb << 6;

  __shared__ ushort hbuf[2][64 * 256];  // 2 x 32 KB, 16B-chunk XOR swizzle

  const uint4* rFd = rF + (size_t)dir * 32768;  // [64 tiles][8 kc][64 lanes]
  const unsigned int* zbase = Zu + (((size_t)dir * 1024 + (rb << 5)) << 15);

  float cst[2][4][4];  // [q][mt][r]
#pragma unroll
  for (int q = 0; q < 2; ++q)
#pragma unroll
    for (int mt = 0; mt < 4; ++mt)
#pragma unroll
      for (int r = 0; r < 4; ++r) cst[q][mt][r] = 0.f;

  for (int t = 0; t < 32; ++t) {
    const int seq = dir ? (31 - t) : t;
    const ushort* hprev = hbuf[(t + 1) & 1];  // h(t-1)
    ushort* hnext = hbuf[t & 1];              // h(t)

#pragma unroll
    for (int q = 0; q < 2; ++q) {
      // ---- issue zx loads (consumed after MFMA; latency hidden) ----
      unsigned int zr[4][4][2];  // [mt][gate][rowpair]
#pragma unroll
      for (int mt = 0; mt < 4; ++mt)
#pragma unroll
        for (int g = 0; g < 4; ++g)
#pragma unroll
          for (int p = 0; p < 2; ++p) {
            const int col = (g << 8) + (w << 5) + (q << 4) + l16;
            const int n2l = (mt << 3) + (kg << 1) + p;
            zr[mt][g][p] = zbase[(((size_t)(n2l << 5) + seq) << 10) + col];
          }

      f32x4 acc[4][4];  // [mt][gate]
#pragma unroll
      for (int mt = 0; mt < 4; ++mt)
#pragma unroll
        for (int g = 0; g < 4; ++g) acc[mt][g] = (f32x4){0.f, 0.f, 0.f, 0.f};

      if (t) {
        uint4 bfr[2][4];
#pragma unroll
        for (int g = 0; g < 4; ++g)
          bfr[0][g] = rFd[(size_t)(((g << 4) + (w << 1) + q) << 3) * 64 + lane];
#pragma unroll
        for (int kc = 0; kc < 8; ++kc) {
          const int cur = kc & 1;
          if (kc < 7) {
#pragma unroll
            for (int g = 0; g < 4; ++g)
              bfr[cur ^ 1][g] =
                  rFd[((size_t)(((g << 4) + (w << 1) + q) << 3) + kc + 1) * 64 +
                      lane];
          }
          uint4 a[4];
#pragma unroll
          for (int mt = 0; mt < 4; ++mt) {
            const int row = (mt << 4) + l16;
            const int c4 = (kc << 2) + kg;
            a[mt] = *(const uint4*)((const char*)hprev + row * 512 +
                                    ((c4 ^ (row & 7)) << 4));
          }
#pragma unroll
          for (int mt = 0; mt < 4; ++mt)
#pragma unroll
            for (int g = 0; g < 4; ++g)
              acc[mt][g] = mfma16(__builtin_bit_cast(bf16x8, a[mt]),
                                  __builtin_bit_cast(bf16x8, bfr[cur][g]),
                                  acc[mt][g]);
        }
      }

      // ---- epilogue: z = acc + zx ; c,h update ; stores ----
      const int col = (w << 5) + (q << 4) + l16;
#pragma unroll
      for (int mt = 0; mt < 4; ++mt) {
#pragma unroll
        for (int r = 0; r < 4; ++r) {
          const int sh = (r & 1) << 4;
          const float zi = acc[mt][0][r] + bf2f((ushort)(zr[mt][0][r >> 1] >> sh));
          const float zf = acc[mt][1][r] + bf2f((ushort)(zr[mt][1][r >> 1] >> sh));
          const float zg = acc[mt][2][r] + bf2f((ushort)(zr[mt][2][r >> 1] >> sh));
          const float zo = acc[mt][3][r] + bf2f((ushort)(zr[mt][3][r >> 1] >> sh));
          const float cn = sigm(zf) * cst[q][mt][r] + sigm(zi) * tanh_(zg);
          cst[q][mt][r] = cn;
          const float hv = sigm(zo) * tanh_(cn);
          const ushort h16 = f2bf(hv);
          const int row = (mt << 4) + (kg << 2) + r;
          *(ushort*)((char*)hnext + row * 512 +
                     (((col >> 3) ^ (row & 7)) << 4) + ((col & 7) << 1)) = h16;
          const int n = rowbase + row, b = n >> 5, sp = n & 31;
          const int X = vert ? seq : sp;
          const int Y = vert ? sp : seq;
          outbuf[(((size_t)(b * 32 + X) * 32 + Y) << 9) + (dir << 8) + col] = h16;
        }
      }
    }
    __syncthreads();  // h(t) complete; all h(t-1) reads done
  }
}

// --------------------------------------------------------------------------
// C = A[M][512] @ BT[1024][512]^T + bias. 128x128 tile, BK=64,
// global_load_lds + XOR swizzle, XCD-aware remap, LDS-staged epilogue.
// EPI 0: pair-interleaved Z store (uint = bf16 row-even | row-odd<<16).
// EPI 1: relu f32 store.
template <int EPI>
__global__ __launch_bounds__(256) void gemm_bt(
    const ushort* __restrict__ A, const ushort* __restrict__ BT,
    const float* __restrict__ bias, void* __restrict__ Cv) {
  const int tid = threadIdx.x;
  const int lane = tid & 63, wid = tid >> 6;
  const int l16 = lane & 15, kg = lane >> 4;
  const int wr = wid >> 1, wc = wid & 1;
  const int bid = blockIdx.x;
  const int xcd = bid & 7, lid = bid >> 3;
  const int m0 = ((xcd << 6) + (lid >> 3)) << 7;
  const int n0 = (lid & 7) << 7;

  union SM {
    struct { uint4 A[128][8]; uint4 B[128][8]; } k;
    ushort eh[64][136];
    float ef[64][132];
  };
  __shared__ SM sm;

  f32x4 acc[4][4];
#pragma unroll
  for (int mt = 0; mt < 4; ++mt)
#pragma unroll
    for (int nt = 0; nt < 4; ++nt) acc[mt][nt] = (f32x4){0.f, 0.f, 0.f, 0.f};

  for (int k0 = 0; k0 < 512; k0 += 64) {
#pragma unroll
    for (int c = 0; c < 4; ++c) {
      const int cid = (wid << 8) + (c << 6) + lane;
      const int row = cid >> 3, ch = cid & 7;
      const int sch = ch ^ (row & 7);
      load_lds16(A + (size_t)(m0 + row) * 512 + k0 + (sch << 3),
                 (uint4*)sm.k.A + (cid - lane));
      load_lds16(BT + (size_t)(n0 + row) * 512 + k0 + (sch << 3),
                 (uint4*)sm.k.B + (cid - lane));
    }
    __syncthreads();
#pragma unroll
    for (int kk = 0; kk < 2; ++kk) {
      const int q = (kk << 2) + kg;
      bf16x8 a[4], b[4];
#pragma unroll
      for (int mt = 0; mt < 4; ++mt) {
        const int rr = (wr << 6) + (mt << 4) + l16;
        a[mt] = __builtin_bit_cast(bf16x8, sm.k.A[rr][q ^ (rr & 7)]);
      }
#pragma unroll
      for (int nt = 0; nt < 4; ++nt) {
        const int rr = (wc << 6) + (nt << 4) + l16;
        b[nt] = __builtin_bit_cast(bf16x8, sm.k.B[rr][q ^ (rr & 7)]);
      }
#pragma unroll
      for (int mt = 0; mt < 4; ++mt)
#pragma unroll
        for (int nt = 0; nt < 4; ++nt)
          acc[mt][nt] = mfma16(a[mt], b[nt], acc[mt][nt]);
    }
    __syncthreads();
  }

  float bn[4];
#pragma unroll
  for (int nt = 0; nt < 4; ++nt)
    bn[nt] = bias[n0 + (wc << 6) + (nt << 4) + l16];

#pragma unroll
  for (int h = 0; h < 2; ++h) {
    __syncthreads();
    if (wr == h) {
#pragma unroll
      for (int nt = 0; nt < 4; ++nt) {
        const int col = (wc << 6) + (nt << 4) + l16;
#pragma unroll
        for (int mt = 0; mt < 4; ++mt) {
#pragma unroll
          for (int r = 0; r < 4; ++r) {
            const int rowl = (mt << 4) + (kg << 2) + r;
            const float v = acc[mt][nt][r] + bn[nt];
            if (EPI == 0)
              sm.eh[rowl][col] = f2bf(v);
            else
              sm.ef[rowl][col] = fmaxf(v, 0.f);
          }
        }
      }
    }
    __syncthreads();
    if (EPI == 0) {
      // rows of this half = i-pair {2h, 2h+1} x 32 seq (m = n*32 + seq)
      unsigned int* out = (unsigned int*)Cv;
      const int n2 = (m0 >> 6) + h;
#pragma unroll
      for (int it = 0; it < 16; ++it) {
        const int e = tid + (it << 8);  // 0..4095
        const int seq = e >> 7, col = e & 127;
        const unsigned int v0 = sm.eh[seq][col];
        const unsigned int v1 = sm.eh[32 + seq][col];
        out[((size_t)(n2 * 32 + seq) << 10) + n0 + col] = v0 | (v1 << 16);
      }
    } else {
      float* out = (float*)Cv;
#pragma unroll
      for (int q = 0; q < 8; ++q) {
        const int c = tid + (q << 8);
        const int row = c >> 5, co = (c & 31) << 2;
        const f32x4 v = *(const f32x4*)&sm.ef[row][co];
        __builtin_nontemporal_store(
            v, (f32x4*)(out + (size_t)(m0 + (h << 6) + row) * 1024 + n0 + co));
      }
    }
  }
}

}  // namespace

extern "C" void kernel_launch(void* const* d_in, const int* in_sizes, int n_in,
                              void* d_out, int out_size, void* d_ws, size_t ws_size,
                              hipStream_t stream) {
  (void)in_sizes; (void)n_in; (void)out_size; (void)ws_size;
  const float* x    = (const float*)d_in[0];
  const float* k_ud = (const float*)d_in[1];
  const float* r_ud = (const float*)d_in[2];
  const float* b_ud = (const float*)d_in[3];
  const float* k_du = (const float*)d_in[4];
  const float* r_du = (const float*)d_in[5];
  const float* b_du = (const float*)d_in[6];
  const float* k_lr = (const float*)d_in[7];
  const float* r_lr = (const float*)d_in[8];
  const float* b_lr = (const float*)d_in[9];
  const float* k_rl = (const float*)d_in[10];
  const float* r_rl = (const float*)d_in[11];
  const float* b_rl = (const float*)d_in[12];
  const float* Wd   = (const float*)d_in[13];
  const float* bd   = (const float*)d_in[14];

  ushort* W    = (ushort*)d_ws;
  ushort* Z    = W;                      // [2][1024 n2][32][1024][2]  134217728
  ushort* vbuf = Z + 134217728;          // [64][32][32][512]           33554432
  ushort* rF   = vbuf + 33554432;        // [4][64][8][64][8]            1048576
  ushort* kTh  = rF + 1048576;           // [2][1024][512]               1048576
  ushort* WdT  = kTh + 1048576;          // [1024][512]                   524288

  // ---- weight prep ----
  rfrag_kernel<<<128, 256, 0, stream>>>(r_ud, rF);
  rfrag_kernel<<<128, 256, 0, stream>>>(r_du, rF + 262144);
  rfrag_kernel<<<128, 256, 0, stream>>>(r_lr, rF + 524288);
  rfrag_kernel<<<128, 256, 0, stream>>>(r_rl, rF + 786432);
  transpose_bf16<<<2048, 256, 0, stream>>>(k_lr, kTh, 512);
  transpose_bf16<<<2048, 256, 0, stream>>>(k_rl, kTh + 524288, 512);
  transpose_bf16<<<2048, 256, 0, stream>>>(Wd, WdT, 512);

  // ---- vertical input projection (K=12), pair-interleaved Z ----
  zxv2_kernel<<<dim3(16, 64, 2), 256, 0, stream>>>(x, k_ud, b_ud, k_du, b_du,
                                                   (unsigned int*)Z);

  // ---- vertical sweep ----
  lstm_sweep3<<<dim3(32, 2), 512, 0, stream>>>((const unsigned int*)Z,
                                               (const uint4*)rF, vbuf, 1);

  // ---- horizontal input projection: Z = v @ k + b (per dir) ----
  gemm_bt<0><<<4096, 256, 0, stream>>>(vbuf, kTh, b_lr, (void*)Z);
  gemm_bt<0><<<4096, 256, 0, stream>>>(vbuf, kTh + 524288, b_rl,
                                       (void*)(Z + 67108864));

  // ---- horizontal sweep (writes hfin over vbuf; reads only Z) ----
  lstm_sweep3<<<dim3(32, 2), 512, 0, stream>>>(
      (const unsigned int*)Z, (const uint4*)(rF + 524288), vbuf, 0);

  // ---- dense + relu ----
  gemm_bt<1><<<4096, 256, 0, stream>>>(vbuf, WdT, bd, d_out);
}